// Round 22
// baseline (106.455 us; speedup 1.0000x reference)
//
#include <hip/hip_runtime.h>
#include <hip/hip_bf16.h>

#define Bn 16
#define Cn 256
#define Tn 8192
#define TFn 512
#define HIDn 256
#define HEADSn 8
#define HDn 32
#define T2n (Tn/2)
#define TW 256
#define T2W 128
#define XPAD 264
#define CKP 72

#define XSWZ(row) ((((row) >> 3) & 7) << 3)

// ws float-index layout:
#define WS_CS   0
#define WS_CC   4096
#define WS_CQ   8192
#define WS_G    12288
#define WS_H    16384
#define WS_QKB  20480
#define WS_QA   20608
#define WS_QH   20736
#define WS_AV   20864
#define WS_BV   24960
#define WS_BF16 29056
#define BF_QKW2 0
#define BF_WV2  65536
#define BF_PROJ 1114112

typedef __attribute__((ext_vector_type(8))) __bf16 bf16x8;
typedef __attribute__((ext_vector_type(4))) __bf16 bf16x4;
typedef __attribute__((ext_vector_type(4))) float f32x4;

// ---------------- prepA: 768-row GEMV, wave-cooperative ---------------------
__global__ __launch_bounds__(256)
void prepA_kernel(const float* __restrict__ temb,
                  const float* __restrict__ ss_w, const float* __restrict__ ss_b,
                  const float* __restrict__ qt_w, const float* __restrict__ qt_b,
                  const float* __restrict__ qw, float* __restrict__ ws)
{
    const int p = blockIdx.x;
    const int b = blockIdx.y;
    const int tid = threadIdx.x, lane = tid & 63, w = tid >> 6;
    __shared__ float st[TFn];
    for (int i = tid; i < TFn; i += 256) {
        float v = temb[b*TFn + i];
        st[i] = v / (1.f + __expf(-v));
    }
    __syncthreads();
    float4 s1 = *(const float4*)&st[lane*8];
    float4 s2 = *(const float4*)&st[lane*8 + 4];
    for (int i = 0; i < 16; ++i) {
        int row = p*64 + w*16 + i;
        const float* W = (row < 2*Cn) ? (ss_w + (size_t)row*TFn)
                                      : (qt_w + (size_t)(row - 2*Cn)*TFn);
        float4 a = *(const float4*)&W[lane*8];
        float4 c = *(const float4*)&W[lane*8 + 4];
        float d = a.x*s1.x + a.y*s1.y + a.z*s1.z + a.w*s1.w
                + c.x*s2.x + c.y*s2.y + c.z*s2.z + c.w*s2.w;
        #pragma unroll
        for (int off = 1; off < 64; off <<= 1) d += __shfl_xor(d, off);
        if (lane == 0) {
            if (row < Cn)
                ws[WS_CS + b*Cn + row] = d + ss_b[row];
            else if (row < 2*Cn)
                ws[WS_CC + b*Cn + (row - Cn)] = d + ss_b[row];
            else
                ws[WS_CQ + b*Cn + (row - 2*Cn)] = d + qt_b[row - 2*Cn] + qw[row - 2*Cn];
        }
    }
}

// ---------------- prepB ------------------------------------------------------
__global__ __launch_bounds__(256)
void prepB_kernel(const float* __restrict__ ln_w, const float* __restrict__ ln_b,
                  const float* __restrict__ kv_w, const float* __restrict__ kv_b,
                  float* __restrict__ ws)
{
    const int b = blockIdx.x, tid = threadIdx.x;
    __bf16* bfr = (__bf16*)(ws + WS_BF16);
    __shared__ float qbs[HIDn], gs[Cn], hs[Cn];
    __shared__ float pA[4][8], pH[4][8];
    const int c = tid, wv = tid >> 6, ln = tid & 63;

    float sc1 = 1.f + ws[WS_CC + b*Cn + c];
    float g = ln_w[c] * sc1;
    float h = ln_b[c] * sc1 + ws[WS_CS + b*Cn + c];
    gs[c] = g; hs[c] = h;
    ws[WS_G + b*Cn + c] = g;
    ws[WS_H + b*Cn + c] = h;
    qbs[c] = ws[WS_CQ + b*Cn + c];
    __syncthreads();

    __bf16* qkw2B = bfr + BF_QKW2 + b*16*Cn;
    for (int hh2 = 0; hh2 < HEADSn; ++hh2) {
        float accq = 0.f;
        #pragma unroll
        for (int d = 0; d < HDn; ++d)
            accq += qbs[hh2*HDn + d] * kv_w[(size_t)(hh2*HDn + d)*Cn + c];
        float wg = accq * gs[c];
        float wh = accq * hs[c];
        qkw2B[hh2*Cn + c] = (__bf16)wg;
        float ra = wg, rh = wh;
        #pragma unroll
        for (int off = 1; off < 64; off <<= 1) {
            ra += __shfl_xor(ra, off);
            rh += __shfl_xor(rh, off);
        }
        if (ln == 0) { pA[wv][hh2] = ra; pH[wv][hh2] = rh; }
    }
    for (int i = tid; i < 8*Cn; i += 256) qkw2B[8*Cn + i] = (__bf16)0.f;
    __syncthreads();
    if (tid < HEADSn) {
        ws[WS_QA + b*8 + tid] = pA[0][tid]+pA[1][tid]+pA[2][tid]+pA[3][tid];
        ws[WS_QH + b*8 + tid] = pH[0][tid]+pH[1][tid]+pH[2][tid]+pH[3][tid];
        float accb = 0.f;
        #pragma unroll
        for (int d = 0; d < HDn; ++d) accb += qbs[tid*HDn + d]*kv_b[tid*HDn + d];
        ws[WS_QKB + b*8 + tid] = accb;
    }
}

// ---------------- prep2 ------------------------------------------------------
__global__ __launch_bounds__(256)
void prep2_kernel(const float* __restrict__ kv_w, const float* __restrict__ kv_b,
                  const float* __restrict__ proj_w, float* __restrict__ ws)
{
    const int tid = threadIdx.x, blk = blockIdx.x;
    __bf16* bfr = (__bf16*)(ws + WS_BF16);
    if (blk < 256) {
        int b  = blk >> 4, ch = blk & 15;
        int rr = tid >> 4, jj = tid & 15;
        int d  = ch*16 + rr;
        const float* gb = ws + WS_G + b*Cn;
        const float* hb = ws + WS_H + b*Cn;
        const float* wrow = kv_w + (size_t)(Cn + d)*Cn;
        __bf16* dst = bfr + BF_WV2 + (size_t)b*Cn*Cn + (size_t)d*Cn;
        float sa = 0.f, sb = 0.f;
        #pragma unroll
        for (int kk = 0; kk < 2; ++kk) {
            bf16x8 pk;
            #pragma unroll
            for (int j = 0; j < 8; ++j) {
                int cc = jj*16 + kk*8 + j;
                float v = wrow[cc], g = gb[cc];
                float vg = v*g;
                pk[j] = (__bf16)vg;
                sa += vg;
                sb += v*hb[cc];
            }
            *(bf16x8*)&dst[jj*16 + kk*8] = pk;
        }
        #pragma unroll
        for (int off = 1; off < 16; off <<= 1) {
            sa += __shfl_xor(sa, off);
            sb += __shfl_xor(sb, off);
        }
        if (jj == 0) {
            ws[WS_AV + b*Cn + d] = sa;
            ws[WS_BV + b*Cn + d] = sb + kv_b[Cn + d];
        }
    } else {
        size_t i0 = (size_t)(blk - 256)*4096 + (size_t)tid*16;
        #pragma unroll
        for (int kk = 0; kk < 2; ++kk) {
            bf16x8 pk;
            #pragma unroll
            for (int j = 0; j < 8; ++j) pk[j] = (__bf16)proj_w[i0 + kk*8 + j];
            *(bf16x8*)&bfr[BF_PROJ + i0 + kk*8] = pk;
        }
    }
}

// ------- main fused kernel: 512 thr, 256-t tile, deep-issue chunk pipeline --
__global__ __launch_bounds__(512, 2)
void qna_main(const float* __restrict__ x, const float* __restrict__ rpe,
              const float* __restrict__ proj_b,
              const float* __restrict__ ws, float* __restrict__ out)
{
    __shared__ __bf16 xcb[2][TW][CKP];   // 73728 B; reused as oT[128][XPAD]
    __shared__ float spool[4096];        // stats partials; reused as aw[8][256]
    __shared__ float ivs[TW], mivs[TW];
    __shared__ float AvS[Cn], BvS[Cn], pbs[Cn];
    __shared__ float qAs[8], qHs[8], qkbs2[8];
    __shared__ float rpes[8][2];

    const int tid  = threadIdx.x;
    const int bt   = blockIdx.x;          // t-tile 0..31
    const int b    = blockIdx.y;
    const int lane = tid & 63;
    const int w    = tid >> 6;            // wave 0..7
    const int r    = lane & 15;
    const int qq   = lane >> 4;

    const __bf16* bfr   = (const __bf16*)(ws + WS_BF16);
    const __bf16* qkw2B = bfr + BF_QKW2 + b*16*Cn;
    const __bf16* Wv2B  = bfr + BF_WV2 + (size_t)b*Cn*Cn;
    const __bf16* projB = bfr + BF_PROJ;

    // ---- phase 0: per-batch params ----
    if (tid < 256) {
        AvS[tid] = ws[WS_AV + b*Cn + tid];
        BvS[tid] = ws[WS_BV + b*Cn + tid];
    } else {
        int t2 = tid - 256;
        pbs[t2] = proj_b[t2];
        if (t2 < 8) {
            qAs[t2]   = ws[WS_QA + b*8 + t2];
            qHs[t2]   = ws[WS_QH + b*8 + t2];
            qkbs2[t2] = ws[WS_QKB + b*8 + t2];
        }
        if (t2 >= 16 && t2 < 32) rpes[(t2-16)>>1][t2&1] = rpe[t2-16];
    }

    // ---- staging: wave w owns chunk c-rows [8w,8w+8); lane t = 4*lane..+3 ----
    const size_t xbase = (size_t)b*Cn*Tn + (size_t)bt*TW + 4*lane;
    const int tL = 4*lane;
    float4 vA[4], vB[4];
    float4 s4 = {0,0,0,0}, q4 = {0,0,0,0};

    auto issueAB = [&](int ch) {   // all 8 rows of next chunk: 8 KB/wave in flight
        #pragma unroll
        for (int i = 0; i < 4; ++i)
            vA[i] = *(const float4*)&x[xbase + (size_t)(ch*64 + 8*w + i)*Tn];
        #pragma unroll
        for (int i = 0; i < 4; ++i)
            vB[i] = *(const float4*)&x[xbase + (size_t)(ch*64 + 8*w + 4 + i)*Tn];
    };
    auto stageAB = [&](int BUF) {
        #pragma unroll
        for (int i = 0; i < 4; ++i) {
            s4.x += vA[i].x; s4.y += vA[i].y; s4.z += vA[i].z; s4.w += vA[i].w;
            q4.x += vA[i].x*vA[i].x; q4.y += vA[i].y*vA[i].y;
            q4.z += vA[i].z*vA[i].z; q4.w += vA[i].w*vA[i].w;
        }
        #pragma unroll
        for (int j = 0; j < 4; ++j) {
            int t = tL + j;
            bf16x4 pk;
            pk[0] = (__bf16)((const float*)&vA[0])[j];
            pk[1] = (__bf16)((const float*)&vA[1])[j];
            pk[2] = (__bf16)((const float*)&vA[2])[j];
            pk[3] = (__bf16)((const float*)&vA[3])[j];
            *(bf16x4*)&xcb[BUF][t][(8*w) ^ XSWZ(t)] = pk;
        }
        #pragma unroll
        for (int i = 0; i < 4; ++i) {
            s4.x += vB[i].x; s4.y += vB[i].y; s4.z += vB[i].z; s4.w += vB[i].w;
            q4.x += vB[i].x*vB[i].x; q4.y += vB[i].y*vB[i].y;
            q4.z += vB[i].z*vB[i].z; q4.w += vB[i].w*vB[i].w;
        }
        #pragma unroll
        for (int j = 0; j < 4; ++j) {
            int t = tL + j;
            bf16x4 pk;
            pk[0] = (__bf16)((const float*)&vB[0])[j];
            pk[1] = (__bf16)((const float*)&vB[1])[j];
            pk[2] = (__bf16)((const float*)&vB[2])[j];
            pk[3] = (__bf16)((const float*)&vB[3])[j];
            *(bf16x4*)&xcb[BUF][t][((8*w) ^ XSWZ(t)) + 4] = pk;
        }
    };

    // prologue: chunk0 staged
    issueAB(0);
    stageAB(0);
    __syncthreads();   // buf0 ready

    // ---- fused logits + V-GEMM over 4 chunks, ONE barrier per chunk ----
    // order: issueAB(ch+1) [8KB in flight] | MFMA(ch) hides latency |
    //        stageAB(ch+1 -> buf^1) | barrier
    f32x4 accL[2];
    accL[0] = (f32x4){0.f,0.f,0.f,0.f};
    accL[1] = (f32x4){0.f,0.f,0.f,0.f};
    f32x4 acc[4][8];
    #pragma unroll
    for (int m = 0; m < 4; ++m)
        #pragma unroll
        for (int n = 0; n < 8; ++n) acc[m][n] = (f32x4){0.f,0.f,0.f,0.f};
    const int d0 = (w & 3) * 64;
    const int tb = (w >> 2) * 128;

    #pragma unroll 1
    for (int ch = 0; ch < 4; ++ch) {
        const int cur = ch & 1;
        if (ch < 3) issueAB(ch + 1);
        #pragma unroll
        for (int k0 = 0; k0 < 2; ++k0) {
            const int kc = ch*64 + k0*32 + qq*8;
            const int cl = k0*32 + qq*8;
            __builtin_amdgcn_s_setprio(1);
            // logits
            {
                bf16x8 aQ = *(const bf16x8*)&qkw2B[(size_t)r*Cn + kc];
                #pragma unroll
                for (int u = 0; u < 2; ++u) {
                    const int trow = (2*w + u)*16 + r;
                    bf16x8 bq = *(const bf16x8*)&xcb[cur][trow][cl ^ XSWZ(trow)];
                    accL[u] = __builtin_amdgcn_mfma_f32_16x16x32_bf16(aQ, bq, accL[u], 0, 0, 0);
                }
            }
            // V-GEMM: preload A-fragments once, consume B in two halves of 4
            bf16x8 a4[4];
            #pragma unroll
            for (int m = 0; m < 4; ++m)
                a4[m] = *(const bf16x8*)&Wv2B[(size_t)(d0 + m*16 + r)*Cn + kc];
            #pragma unroll
            for (int nh = 0; nh < 2; ++nh) {
                bf16x8 bb[4];
                #pragma unroll
                for (int n = 0; n < 4; ++n) {
                    const int row = tb + (nh*4 + n)*16 + r;
                    bb[n] = *(const bf16x8*)&xcb[cur][row][cl ^ XSWZ(row)];
                }
                #pragma unroll
                for (int m = 0; m < 4; ++m)
                    #pragma unroll
                    for (int n = 0; n < 4; ++n)
                        acc[m][nh*4 + n] = __builtin_amdgcn_mfma_f32_16x16x32_bf16(
                            a4[m], bb[n], acc[m][nh*4 + n], 0, 0, 0);
            }
            __builtin_amdgcn_s_setprio(0);
        }
        if (ch < 3) {
            stageAB(cur ^ 1);
            if (ch == 2) {   // stats complete (all 4 chunks accumulated)
                spool[0*512 + w*64 + lane] = s4.x;
                spool[1*512 + w*64 + lane] = s4.y;
                spool[2*512 + w*64 + lane] = s4.z;
                spool[3*512 + w*64 + lane] = s4.w;
                spool[2048 + 0*512 + w*64 + lane] = q4.x;
                spool[2048 + 1*512 + w*64 + lane] = q4.y;
                spool[2048 + 2*512 + w*64 + lane] = q4.z;
                spool[2048 + 3*512 + w*64 + lane] = q4.w;
            }
            __syncthreads();   // buf[cur^1] staged; readers of buf[cur] done
        }
    }

    // ---- stats reduce (tid<256); spool visible since ch==2 barrier ----
    if (tid < 256) {
        const int t = tid, comp = t & 3, lq = t >> 2;
        float s = 0.f, sq = 0.f;
        #pragma unroll
        for (int w2 = 0; w2 < 8; ++w2) {
            s  += spool[comp*512 + w2*64 + lq];
            sq += spool[2048 + comp*512 + w2*64 + lq];
        }
        float mean = s * (1.f/Cn);
        float var  = sq * (1.f/Cn) - mean*mean;
        float iv   = rsqrtf(var + 1e-6f);
        ivs[t]  = iv;
        mivs[t] = mean * iv;
    }
    __syncthreads();   // F: ivs ready; every wave past MFMA(3)

    // ---- softmax -> aw (spool region) ----
    float* aw = spool;
    {
        const float sc = 0.17677669529663687f;
        #pragma unroll
        for (int u = 0; u < 2; ++u) {
            const int tcol = (2*w + u)*16 + r;
            float iv = ivs[tcol], miv = mivs[tcol];
            #pragma unroll
            for (int rr = 0; rr < 4; ++rr) {
                int h  = (qq*4 + rr) & 7;
                float l = (accL[u][rr]*iv - miv*qAs[h] + qHs[h] + qkbs2[h])*sc + rpes[h][r&1];
                float mx = fmaxf(l, __shfl_xor(l, 1));
                float e  = __expf(l - mx);
                float sm = e + __shfl_xor(e, 1);
                float aval = e / sm;
                if (qq < 2) aw[(qq*4 + rr)*256 + tcol] = aval;
            }
        }
    }
    __syncthreads();   // G: aw ready; xcb free

    // ---- V-correct + attn combine -> bf16 oT[u][d] (xcb region) ----
    __bf16* oTp = &xcb[0][0][0];
    {
        #pragma unroll
        for (int m = 0; m < 4; ++m) {
            const int dbase = d0 + m*16 + qq*4;
            const int h = dbase >> 5;
            float av4[4], bv4[4];
            #pragma unroll
            for (int rr = 0; rr < 4; ++rr) { av4[rr] = AvS[dbase+rr]; bv4[rr] = BvS[dbase+rr]; }
            #pragma unroll
            for (int n = 0; n < 8; ++n) {
                const int tl = tb + n*16 + r;
                float ivn = ivs[tl], mivn = mivs[tl];
                float a0 = aw[h*256 + (tl & ~1)], a1 = aw[h*256 + (tl | 1)];
                bf16x4 ov;
                #pragma unroll
                for (int rr = 0; rr < 4; ++rr) {
                    float vv = ivn*acc[m][n][rr] - mivn*av4[rr] + bv4[rr];
                    float vo = __shfl_xor(vv, 1);
                    float o  = a0*vv + a1*vo;
                    ov[rr] = (__bf16)o;
                }
                if (!(r & 1)) {
                    int u = (tb >> 1) + n*8 + (r >> 1);
                    *(bf16x4*)&oTp[(size_t)u*XPAD + dbase] = ov;
                }
            }
        }
    }
    __syncthreads();   // H: oT ready

    // ---- proj GEMM ----
    const int t2b = (w >> 2) * 64;
    f32x4 acc2[4][4];
    #pragma unroll
    for (int m = 0; m < 4; ++m)
        #pragma unroll
        for (int n = 0; n < 4; ++n) acc2[m][n] = (f32x4){0.f,0.f,0.f,0.f};
    #pragma unroll
    for (int k0 = 0; k0 < 8; ++k0) {
        bf16x8 bb2[4];
        #pragma unroll
        for (int n = 0; n < 4; ++n)
            bb2[n] = *(const bf16x8*)&oTp[(size_t)(t2b + n*16 + r)*XPAD + k0*32 + qq*8];
        #pragma unroll
        for (int m = 0; m < 4; ++m) {
            bf16x8 a = *(const bf16x8*)&projB[(size_t)(d0 + m*16 + r)*Cn + k0*32 + qq*8];
            #pragma unroll
            for (int n = 0; n < 4; ++n)
                acc2[m][n] = __builtin_amdgcn_mfma_f32_16x16x32_bf16(a, bb2[n], acc2[m][n], 0, 0, 0);
        }
    }

    // ---- epilogue: bias + store fp32 ----
    {
        float* ob = out + (size_t)b*HIDn*T2n + (size_t)bt*T2W;
        #pragma unroll
        for (int m = 0; m < 4; ++m) {
            #pragma unroll
            for (int n = 0; n < 4; ++n) {
                #pragma unroll
                for (int rr = 0; rr < 4; ++rr) {
                    int e = d0 + m*16 + qq*4 + rr;
                    ob[(size_t)e*T2n + t2b + n*16 + r] = acc2[m][n][rr] + pbs[e];
                }
            }
        }
    }
}

extern "C" void kernel_launch(void* const* d_in, const int* in_sizes, int n_in,
                              void* d_out, int out_size, void* d_ws, size_t ws_size,
                              hipStream_t stream) {
    (void)in_sizes; (void)n_in; (void)out_size; (void)ws_size;
    const float* x      = (const float*)d_in[0];
    const float* temb   = (const float*)d_in[1];
    const float* ln_w   = (const float*)d_in[2];
    const float* ln_b   = (const float*)d_in[3];
    const float* ss_w   = (const float*)d_in[4];
    const float* ss_b   = (const float*)d_in[5];
    const float* kv_w   = (const float*)d_in[6];
    const float* kv_b   = (const float*)d_in[7];
    const float* q      = (const float*)d_in[8];
    const float* qt_w   = (const float*)d_in[9];
    const float* qt_b   = (const float*)d_in[10];
    const float* rpe    = (const float*)d_in[11];
    const float* proj_w = (const float*)d_in[12];
    const float* proj_b = (const float*)d_in[13];
    float* ws  = (float*)d_ws;
    float* out = (float*)d_out;

    prepA_kernel<<<dim3(12, Bn), dim3(256), 0, stream>>>(
        temb, ss_w, ss_b, qt_w, qt_b, q, ws);
    prepB_kernel<<<dim3(Bn), dim3(256), 0, stream>>>(ln_w, ln_b, kv_w, kv_b, ws);
    prep2_kernel<<<dim3(272), dim3(256), 0, stream>>>(kv_w, kv_b, proj_w, ws);
    qna_main<<<dim3(Tn/TW, Bn), dim3(512), 0, stream>>>(x, rpe, proj_b, ws, out);
}

// Round 23
// 102.033 us; speedup vs baseline: 1.0433x; 1.0433x over previous
//
#include <hip/hip_runtime.h>
#include <hip/hip_bf16.h>

#define Bn 16
#define Cn 256
#define Tn 8192
#define TFn 512
#define HIDn 256
#define HEADSn 8
#define HDn 32
#define T2n (Tn/2)
#define TW 256
#define T2W 128
#define XPAD 264
#define CKP 72

#define XSWZ(row) ((((row) >> 3) & 7) << 3)

// ws float-index layout:
#define WS_CS   0
#define WS_CC   4096
#define WS_CQ   8192
#define WS_G    12288
#define WS_H    16384
#define WS_QKB  20480
#define WS_QA   20608
#define WS_QH   20736
#define WS_AV   20864
#define WS_BV   24960
#define WS_BF16 29056
#define BF_QKW2 0
#define BF_WV2  65536
#define BF_PROJ 1114112

typedef __attribute__((ext_vector_type(8))) __bf16 bf16x8;
typedef __attribute__((ext_vector_type(4))) __bf16 bf16x4;
typedef __attribute__((ext_vector_type(4))) float f32x4;

// ---------------- prepA: 768-row GEMV, wave-cooperative ---------------------
__global__ __launch_bounds__(256)
void prepA_kernel(const float* __restrict__ temb,
                  const float* __restrict__ ss_w, const float* __restrict__ ss_b,
                  const float* __restrict__ qt_w, const float* __restrict__ qt_b,
                  const float* __restrict__ qw, float* __restrict__ ws)
{
    const int p = blockIdx.x;
    const int b = blockIdx.y;
    const int tid = threadIdx.x, lane = tid & 63, w = tid >> 6;
    __shared__ float st[TFn];
    for (int i = tid; i < TFn; i += 256) {
        float v = temb[b*TFn + i];
        st[i] = v / (1.f + __expf(-v));
    }
    __syncthreads();
    float4 s1 = *(const float4*)&st[lane*8];
    float4 s2 = *(const float4*)&st[lane*8 + 4];
    for (int i = 0; i < 16; ++i) {
        int row = p*64 + w*16 + i;
        const float* W = (row < 2*Cn) ? (ss_w + (size_t)row*TFn)
                                      : (qt_w + (size_t)(row - 2*Cn)*TFn);
        float4 a = *(const float4*)&W[lane*8];
        float4 c = *(const float4*)&W[lane*8 + 4];
        float d = a.x*s1.x + a.y*s1.y + a.z*s1.z + a.w*s1.w
                + c.x*s2.x + c.y*s2.y + c.z*s2.z + c.w*s2.w;
        #pragma unroll
        for (int off = 1; off < 64; off <<= 1) d += __shfl_xor(d, off);
        if (lane == 0) {
            if (row < Cn)
                ws[WS_CS + b*Cn + row] = d + ss_b[row];
            else if (row < 2*Cn)
                ws[WS_CC + b*Cn + (row - Cn)] = d + ss_b[row];
            else
                ws[WS_CQ + b*Cn + (row - 2*Cn)] = d + qt_b[row - 2*Cn] + qw[row - 2*Cn];
        }
    }
}

// ---------------- prepB ------------------------------------------------------
__global__ __launch_bounds__(256)
void prepB_kernel(const float* __restrict__ ln_w, const float* __restrict__ ln_b,
                  const float* __restrict__ kv_w, const float* __restrict__ kv_b,
                  float* __restrict__ ws)
{
    const int b = blockIdx.x, tid = threadIdx.x;
    __bf16* bfr = (__bf16*)(ws + WS_BF16);
    __shared__ float qbs[HIDn], gs[Cn], hs[Cn];
    __shared__ float pA[4][8], pH[4][8];
    const int c = tid, wv = tid >> 6, ln = tid & 63;

    float sc1 = 1.f + ws[WS_CC + b*Cn + c];
    float g = ln_w[c] * sc1;
    float h = ln_b[c] * sc1 + ws[WS_CS + b*Cn + c];
    gs[c] = g; hs[c] = h;
    ws[WS_G + b*Cn + c] = g;
    ws[WS_H + b*Cn + c] = h;
    qbs[c] = ws[WS_CQ + b*Cn + c];
    __syncthreads();

    __bf16* qkw2B = bfr + BF_QKW2 + b*16*Cn;
    for (int hh2 = 0; hh2 < HEADSn; ++hh2) {
        float accq = 0.f;
        #pragma unroll
        for (int d = 0; d < HDn; ++d)
            accq += qbs[hh2*HDn + d] * kv_w[(size_t)(hh2*HDn + d)*Cn + c];
        float wg = accq * gs[c];
        float wh = accq * hs[c];
        qkw2B[hh2*Cn + c] = (__bf16)wg;
        float ra = wg, rh = wh;
        #pragma unroll
        for (int off = 1; off < 64; off <<= 1) {
            ra += __shfl_xor(ra, off);
            rh += __shfl_xor(rh, off);
        }
        if (ln == 0) { pA[wv][hh2] = ra; pH[wv][hh2] = rh; }
    }
    for (int i = tid; i < 8*Cn; i += 256) qkw2B[8*Cn + i] = (__bf16)0.f;
    __syncthreads();
    if (tid < HEADSn) {
        ws[WS_QA + b*8 + tid] = pA[0][tid]+pA[1][tid]+pA[2][tid]+pA[3][tid];
        ws[WS_QH + b*8 + tid] = pH[0][tid]+pH[1][tid]+pH[2][tid]+pH[3][tid];
        float accb = 0.f;
        #pragma unroll
        for (int d = 0; d < HDn; ++d) accb += qbs[tid*HDn + d]*kv_b[tid*HDn + d];
        ws[WS_QKB + b*8 + tid] = accb;
    }
}

// ---------------- prep2 ------------------------------------------------------
__global__ __launch_bounds__(256)
void prep2_kernel(const float* __restrict__ kv_w, const float* __restrict__ kv_b,
                  const float* __restrict__ proj_w, float* __restrict__ ws)
{
    const int tid = threadIdx.x, blk = blockIdx.x;
    __bf16* bfr = (__bf16*)(ws + WS_BF16);
    if (blk < 256) {
        int b  = blk >> 4, ch = blk & 15;
        int rr = tid >> 4, jj = tid & 15;
        int d  = ch*16 + rr;
        const float* gb = ws + WS_G + b*Cn;
        const float* hb = ws + WS_H + b*Cn;
        const float* wrow = kv_w + (size_t)(Cn + d)*Cn;
        __bf16* dst = bfr + BF_WV2 + (size_t)b*Cn*Cn + (size_t)d*Cn;
        float sa = 0.f, sb = 0.f;
        #pragma unroll
        for (int kk = 0; kk < 2; ++kk) {
            bf16x8 pk;
            #pragma unroll
            for (int j = 0; j < 8; ++j) {
                int cc = jj*16 + kk*8 + j;
                float v = wrow[cc], g = gb[cc];
                float vg = v*g;
                pk[j] = (__bf16)vg;
                sa += vg;
                sb += v*hb[cc];
            }
            *(bf16x8*)&dst[jj*16 + kk*8] = pk;
        }
        #pragma unroll
        for (int off = 1; off < 16; off <<= 1) {
            sa += __shfl_xor(sa, off);
            sb += __shfl_xor(sb, off);
        }
        if (jj == 0) {
            ws[WS_AV + b*Cn + d] = sa;
            ws[WS_BV + b*Cn + d] = sb + kv_b[Cn + d];
        }
    } else {
        size_t i0 = (size_t)(blk - 256)*4096 + (size_t)tid*16;
        #pragma unroll
        for (int kk = 0; kk < 2; ++kk) {
            bf16x8 pk;
            #pragma unroll
            for (int j = 0; j < 8; ++j) pk[j] = (__bf16)proj_w[i0 + kk*8 + j];
            *(bf16x8*)&bfr[BF_PROJ + i0 + kk*8] = pk;
        }
    }
}

// ------- main fused kernel: 512 thr, 256-t tile, 1-barrier chunk pipeline ---
__global__ __launch_bounds__(512, 2)
void qna_main(const float* __restrict__ x, const float* __restrict__ rpe,
              const float* __restrict__ proj_b,
              const float* __restrict__ ws, float* __restrict__ out)
{
    __shared__ __bf16 xcb[2][TW][CKP];   // 73728 B; reused as oT[128][XPAD]
    __shared__ float spool[4096];        // stats partials; reused as aw[8][256]
    __shared__ float ivs[TW], mivs[TW];
    __shared__ float AvS[Cn], BvS[Cn], pbs[Cn];
    __shared__ float qAs[8], qHs[8], qkbs2[8];
    __shared__ float rpes[8][2];

    const int tid  = threadIdx.x;
    const int bt   = blockIdx.x;          // t-tile 0..31
    const int b    = blockIdx.y;
    const int lane = tid & 63;
    const int w    = tid >> 6;            // wave 0..7
    const int r    = lane & 15;
    const int qq   = lane >> 4;

    const __bf16* bfr   = (const __bf16*)(ws + WS_BF16);
    const __bf16* qkw2B = bfr + BF_QKW2 + b*16*Cn;
    const __bf16* Wv2B  = bfr + BF_WV2 + (size_t)b*Cn*Cn;
    const __bf16* projB = bfr + BF_PROJ;

    // ---- phase 0: per-batch params ----
    if (tid < 256) {
        AvS[tid] = ws[WS_AV + b*Cn + tid];
        BvS[tid] = ws[WS_BV + b*Cn + tid];
    } else {
        int t2 = tid - 256;
        pbs[t2] = proj_b[t2];
        if (t2 < 8) {
            qAs[t2]   = ws[WS_QA + b*8 + t2];
            qHs[t2]   = ws[WS_QH + b*8 + t2];
            qkbs2[t2] = ws[WS_QKB + b*8 + t2];
        }
        if (t2 >= 16 && t2 < 32) rpes[(t2-16)>>1][t2&1] = rpe[t2-16];
    }

    // ---- staging: wave w owns chunk c-rows [8w,8w+8); lane t = 4*lane..+3 ----
    const size_t xbase = (size_t)b*Cn*Tn + (size_t)bt*TW + 4*lane;
    const int tL = 4*lane;
    float4 vA[4], vB[4];
    float4 s4 = {0,0,0,0}, q4 = {0,0,0,0};

    auto issueA = [&](int ch) {
        #pragma unroll
        for (int i = 0; i < 4; ++i)
            vA[i] = *(const float4*)&x[xbase + (size_t)(ch*64 + 8*w + i)*Tn];
    };
    auto issueB = [&](int ch) {
        #pragma unroll
        for (int i = 0; i < 4; ++i)
            vB[i] = *(const float4*)&x[xbase + (size_t)(ch*64 + 8*w + 4 + i)*Tn];
    };
    auto stageA = [&](int BUF) {
        #pragma unroll
        for (int i = 0; i < 4; ++i) {
            s4.x += vA[i].x; s4.y += vA[i].y; s4.z += vA[i].z; s4.w += vA[i].w;
            q4.x += vA[i].x*vA[i].x; q4.y += vA[i].y*vA[i].y;
            q4.z += vA[i].z*vA[i].z; q4.w += vA[i].w*vA[i].w;
        }
        #pragma unroll
        for (int j = 0; j < 4; ++j) {
            int t = tL + j;
            bf16x4 pk;
            pk[0] = (__bf16)((const float*)&vA[0])[j];
            pk[1] = (__bf16)((const float*)&vA[1])[j];
            pk[2] = (__bf16)((const float*)&vA[2])[j];
            pk[3] = (__bf16)((const float*)&vA[3])[j];
            *(bf16x4*)&xcb[BUF][t][(8*w) ^ XSWZ(t)] = pk;
        }
    };
    auto stageB = [&](int BUF) {
        #pragma unroll
        for (int i = 0; i < 4; ++i) {
            s4.x += vB[i].x; s4.y += vB[i].y; s4.z += vB[i].z; s4.w += vB[i].w;
            q4.x += vB[i].x*vB[i].x; q4.y += vB[i].y*vB[i].y;
            q4.z += vB[i].z*vB[i].z; q4.w += vB[i].w*vB[i].w;
        }
        #pragma unroll
        for (int j = 0; j < 4; ++j) {
            int t = tL + j;
            bf16x4 pk;
            pk[0] = (__bf16)((const float*)&vB[0])[j];
            pk[1] = (__bf16)((const float*)&vB[1])[j];
            pk[2] = (__bf16)((const float*)&vB[2])[j];
            pk[3] = (__bf16)((const float*)&vB[3])[j];
            *(bf16x4*)&xcb[BUF][t][((8*w) ^ XSWZ(t)) + 4] = pk;
        }
    };

    // prologue: chunk0 staged
    issueA(0); issueB(0);
    stageA(0); stageB(0);
    __syncthreads();   // buf0 ready

    // ---- fused logits + V-GEMM over 4 chunks, ONE barrier per chunk ----
    // NOT unrolled: keeps address/live-range pressure at single-iteration level
    f32x4 accL[2];
    accL[0] = (f32x4){0.f,0.f,0.f,0.f};
    accL[1] = (f32x4){0.f,0.f,0.f,0.f};
    f32x4 acc[4][8];
    #pragma unroll
    for (int m = 0; m < 4; ++m)
        #pragma unroll
        for (int n = 0; n < 8; ++n) acc[m][n] = (f32x4){0.f,0.f,0.f,0.f};
    const int d0 = (w & 3) * 64;
    const int tb = (w >> 2) * 128;

    #pragma unroll 1
    for (int ch = 0; ch < 4; ++ch) {
        const int cur = ch & 1;
        if (ch < 3) issueA(ch + 1);
        #pragma unroll
        for (int k0 = 0; k0 < 2; ++k0) {
            const int kc = ch*64 + k0*32 + qq*8;
            const int cl = k0*32 + qq*8;
            // logits
            {
                bf16x8 aQ = *(const bf16x8*)&qkw2B[(size_t)r*Cn + kc];
                #pragma unroll
                for (int u = 0; u < 2; ++u) {
                    const int trow = (2*w + u)*16 + r;
                    bf16x8 bq = *(const bf16x8*)&xcb[cur][trow][cl ^ XSWZ(trow)];
                    accL[u] = __builtin_amdgcn_mfma_f32_16x16x32_bf16(aQ, bq, accL[u], 0, 0, 0);
                }
            }
            // V-GEMM: preload A-fragments once, consume B in two halves of 4
            bf16x8 a4[4];
            #pragma unroll
            for (int m = 0; m < 4; ++m)
                a4[m] = *(const bf16x8*)&Wv2B[(size_t)(d0 + m*16 + r)*Cn + kc];
            #pragma unroll
            for (int nh = 0; nh < 2; ++nh) {
                bf16x8 bb[4];
                #pragma unroll
                for (int n = 0; n < 4; ++n) {
                    const int row = tb + (nh*4 + n)*16 + r;
                    bb[n] = *(const bf16x8*)&xcb[cur][row][cl ^ XSWZ(row)];
                }
                #pragma unroll
                for (int m = 0; m < 4; ++m)
                    #pragma unroll
                    for (int n = 0; n < 4; ++n)
                        acc[m][nh*4 + n] = __builtin_amdgcn_mfma_f32_16x16x32_bf16(
                            a4[m], bb[n], acc[m][nh*4 + n], 0, 0, 0);
            }
            if (k0 == 0 && ch < 3) issueB(ch + 1);   // B-half loads hide under k0=1 MFMA
        }
        if (ch < 3) {
            stageA(cur ^ 1);
            stageB(cur ^ 1);
            if (ch == 2) {   // stats complete (all 4 chunks accumulated)
                spool[0*512 + w*64 + lane] = s4.x;
                spool[1*512 + w*64 + lane] = s4.y;
                spool[2*512 + w*64 + lane] = s4.z;
                spool[3*512 + w*64 + lane] = s4.w;
                spool[2048 + 0*512 + w*64 + lane] = q4.x;
                spool[2048 + 1*512 + w*64 + lane] = q4.y;
                spool[2048 + 2*512 + w*64 + lane] = q4.z;
                spool[2048 + 3*512 + w*64 + lane] = q4.w;
            }
            __syncthreads();   // buf[cur^1] staged; readers of buf[cur] done
        }
    }

    // ---- stats reduce (tid<256); spool visible since ch==2 barrier ----
    if (tid < 256) {
        const int t = tid, comp = t & 3, lq = t >> 2;
        float s = 0.f, sq = 0.f;
        #pragma unroll
        for (int w2 = 0; w2 < 8; ++w2) {
            s  += spool[comp*512 + w2*64 + lq];
            sq += spool[2048 + comp*512 + w2*64 + lq];
        }
        float mean = s * (1.f/Cn);
        float var  = sq * (1.f/Cn) - mean*mean;
        float iv   = rsqrtf(var + 1e-6f);
        ivs[t]  = iv;
        mivs[t] = mean * iv;
    }
    __syncthreads();   // F: ivs ready; every wave past MFMA(3)

    // ---- softmax -> aw (spool region) ----
    float* aw = spool;
    {
        const float sc = 0.17677669529663687f;
        #pragma unroll
        for (int u = 0; u < 2; ++u) {
            const int tcol = (2*w + u)*16 + r;
            float iv = ivs[tcol], miv = mivs[tcol];
            #pragma unroll
            for (int rr = 0; rr < 4; ++rr) {
                int h  = (qq*4 + rr) & 7;
                float l = (accL[u][rr]*iv - miv*qAs[h] + qHs[h] + qkbs2[h])*sc + rpes[h][r&1];
                float mx = fmaxf(l, __shfl_xor(l, 1));
                float e  = __expf(l - mx);
                float sm = e + __shfl_xor(e, 1);
                float aval = e / sm;
                if (qq < 2) aw[(qq*4 + rr)*256 + tcol] = aval;
            }
        }
    }
    __syncthreads();   // G: aw ready; xcb free

    // ---- V-correct + attn combine -> bf16 oT[u][d] (xcb region) ----
    __bf16* oTp = &xcb[0][0][0];
    {
        #pragma unroll
        for (int m = 0; m < 4; ++m) {
            const int dbase = d0 + m*16 + qq*4;
            const int h = dbase >> 5;
            float av4[4], bv4[4];
            #pragma unroll
            for (int rr = 0; rr < 4; ++rr) { av4[rr] = AvS[dbase+rr]; bv4[rr] = BvS[dbase+rr]; }
            #pragma unroll
            for (int n = 0; n < 8; ++n) {
                const int tl = tb + n*16 + r;
                float ivn = ivs[tl], mivn = mivs[tl];
                float a0 = aw[h*256 + (tl & ~1)], a1 = aw[h*256 + (tl | 1)];
                bf16x4 ov;
                #pragma unroll
                for (int rr = 0; rr < 4; ++rr) {
                    float vv = ivn*acc[m][n][rr] - mivn*av4[rr] + bv4[rr];
                    float vo = __shfl_xor(vv, 1);
                    float o  = a0*vv + a1*vo;
                    ov[rr] = (__bf16)o;
                }
                if (!(r & 1)) {
                    int u = (tb >> 1) + n*8 + (r >> 1);
                    *(bf16x4*)&oTp[(size_t)u*XPAD + dbase] = ov;
                }
            }
        }
    }
    __syncthreads();   // H: oT ready

    // ---- proj GEMM ----
    const int t2b = (w >> 2) * 64;
    f32x4 acc2[4][4];
    #pragma unroll
    for (int m = 0; m < 4; ++m)
        #pragma unroll
        for (int n = 0; n < 4; ++n) acc2[m][n] = (f32x4){0.f,0.f,0.f,0.f};
    #pragma unroll
    for (int k0 = 0; k0 < 8; ++k0) {
        bf16x8 bb2[4];
        #pragma unroll
        for (int n = 0; n < 4; ++n)
            bb2[n] = *(const bf16x8*)&oTp[(size_t)(t2b + n*16 + r)*XPAD + k0*32 + qq*8];
        #pragma unroll
        for (int m = 0; m < 4; ++m) {
            bf16x8 a = *(const bf16x8*)&projB[(size_t)(d0 + m*16 + r)*Cn + k0*32 + qq*8];
            #pragma unroll
            for (int n = 0; n < 4; ++n)
                acc2[m][n] = __builtin_amdgcn_mfma_f32_16x16x32_bf16(a, bb2[n], acc2[m][n], 0, 0, 0);
        }
    }

    // ---- epilogue: bias + store fp32 ----
    {
        float* ob = out + (size_t)b*HIDn*T2n + (size_t)bt*T2W;
        #pragma unroll
        for (int m = 0; m < 4; ++m) {
            #pragma unroll
            for (int n = 0; n < 4; ++n) {
                #pragma unroll
                for (int rr = 0; rr < 4; ++rr) {
                    int e = d0 + m*16 + qq*4 + rr;
                    ob[(size_t)e*T2n + t2b + n*16 + r] = acc2[m][n][rr] + pbs[e];
                }
            }
        }
    }
}

extern "C" void kernel_launch(void* const* d_in, const int* in_sizes, int n_in,
                              void* d_out, int out_size, void* d_ws, size_t ws_size,
                              hipStream_t stream) {
    (void)in_sizes; (void)n_in; (void)out_size; (void)ws_size;
    const float* x      = (const float*)d_in[0];
    const float* temb   = (const float*)d_in[1];
    const float* ln_w   = (const float*)d_in[2];
    const float* ln_b   = (const float*)d_in[3];
    const float* ss_w   = (const float*)d_in[4];
    const float* ss_b   = (const float*)d_in[5];
    const float* kv_w   = (const float*)d_in[6];
    const float* kv_b   = (const float*)d_in[7];
    const float* q      = (const float*)d_in[8];
    const float* qt_w   = (const float*)d_in[9];
    const float* qt_b   = (const float*)d_in[10];
    const float* rpe    = (const float*)d_in[11];
    const float* proj_w = (const float*)d_in[12];
    const float* proj_b = (const float*)d_in[13];
    float* ws  = (float*)d_ws;
    float* out = (float*)d_out;

    prepA_kernel<<<dim3(12, Bn), dim3(256), 0, stream>>>(
        temb, ss_w, ss_b, qt_w, qt_b, q, ws);
    prepB_kernel<<<dim3(Bn), dim3(256), 0, stream>>>(ln_w, ln_b, kv_w, kv_b, ws);
    prep2_kernel<<<dim3(272), dim3(256), 0, stream>>>(kv_w, kv_b, proj_w, ws);
    qna_main<<<dim3(Tn/TW, Bn), dim3(512), 0, stream>>>(x, rpe, proj_b, ws, out);
}